// Round 7
// baseline (308.869 us; speedup 1.0000x reference)
//
#include <hip/hip_runtime.h>

#define K_CODES 512
#define DIM     256
#define HW      1024
#define N_ROWS  65536
#define NT      256
#define QBM     128           // rows per block
#define NBLK    (N_ROWS / QBM) // 512
#define MARGIN  0.125f

#define OUT_Q_OFF    16777216
#define OUT_LOSS_OFF 16842752

// ws (floats): [0,512) c2 ; [512,1024) dist partials ; [1024,1536) x2 partials
#define WS_DIST 512
#define WS_X2   1024

typedef __attribute__((ext_vector_type(8))) short short8v;
typedef __attribute__((ext_vector_type(4))) float floatx4;

__device__ __forceinline__ unsigned short bf16_rne(float f) {
    unsigned int u = __float_as_uint(f);
    u += 0x7fffu + ((u >> 16) & 1u);
    return (unsigned short)(u >> 16);
}
__device__ __forceinline__ float bf16_to_f(unsigned short h) {
    unsigned int u = ((unsigned int)h) << 16;
    return __uint_as_float(u);
}
__device__ __forceinline__ uint4 pack8(const unsigned short* h) {
    uint4 u;
    u.x = (unsigned)h[0] | ((unsigned)h[1] << 16);
    u.y = (unsigned)h[2] | ((unsigned)h[3] << 16);
    u.z = (unsigned)h[4] | ((unsigned)h[5] << 16);
    u.w = (unsigned)h[6] | ((unsigned)h[7] << 16);
    return u;
}

__global__ void c2_kernel(const float* __restrict__ lut, float* __restrict__ ws) {
    int t = threadIdx.x;
    for (int k = t; k < K_CODES; k += NT) {
        const float4* row = (const float4*)(lut + (size_t)k * DIM);
        float s = 0.f;
        #pragma unroll 8
        for (int i = 0; i < DIM / 4; ++i) {
            float4 v = row[i];
            s += v.x * v.x + v.y * v.y + v.z * v.z + v.w * v.w;
        }
        ws[k] = s;
    }
}

// rows: 144B stride = [0,64) hi bf16 k0..31, [64,128) lo, [128,144) pad (bank spread)
__global__ __launch_bounds__(NT, 2) void vq_kernel(const float* __restrict__ x,
                                                   const float* __restrict__ lut,
                                                   float* __restrict__ out,
                                                   float* __restrict__ ws) {
    __shared__ char aS[QBM * 144];     // 18 KB
    __shared__ char bS[256 * 144];     // 36 KB
    __shared__ float c2s[K_CODES];     // 2 KB
    __shared__ float redv1[4][QBM];    // 2 KB
    __shared__ float redv2[4][QBM];    // 2 KB
    __shared__ int   redi1[4][QBM];    // 2 KB
    __shared__ float wsumd[4];
    __shared__ float wsumx[4];

    const int tid  = threadIdx.x;
    const int blk  = blockIdx.x;
    const int n0   = blk * QBM;
    const int b    = n0 >> 10;
    const int hw0  = n0 & 1023;
    const float* xb = x + (size_t)b * (DIM * HW) + hw0;

    for (int k = tid; k < K_CODES; k += NT) c2s[k] = ws[k];

    const int wave = tid >> 6;
    const int lane = tid & 63;
    const int l15  = lane & 15;
    const int l4   = lane >> 4;
    const int wr   = wave >> 1;   // row half: rows wr*64..+63
    const int wc   = wave & 1;    // code half within 256-chunk

    // staging maps
    const int srow = tid & 127;          // A: row
    const int sd0  = (tid >> 7) * 16;    // A: d offset 0/16
    // B: code = tid

    float x2local = 0.f;

    for (int kc = 0; kc < 2; ++kc) {
        floatx4 acc[4][8];
        #pragma unroll
        for (int i = 0; i < 4; ++i)
            #pragma unroll
            for (int j = 0; j < 8; ++j) acc[i][j] = (floatx4)0.f;

        for (int dc = 0; dc < 8; ++dc) {
            const int kd0 = dc * 32;
            __syncthreads();
            // ---- stage A: 128 rows x 32 d (hi/lo bf16) ----
            {
                unsigned short hi[16], lo[16];
                #pragma unroll
                for (int j = 0; j < 16; ++j) {
                    float v = xb[(size_t)(kd0 + sd0 + j) * HW + srow];
                    if (kc == 0) x2local = fmaf(v, v, x2local);
                    unsigned short h = bf16_rne(v);
                    hi[j] = h;
                    lo[j] = bf16_rne(v - bf16_to_f(h));
                }
                char* rowb = aS + srow * 144;
                int co = (sd0 >> 3) * 16;          // 0 or 32
                *(uint4*)(rowb + co)        = pack8(hi);
                *(uint4*)(rowb + co + 16)   = pack8(hi + 8);
                *(uint4*)(rowb + 64 + co)      = pack8(lo);
                *(uint4*)(rowb + 64 + co + 16) = pack8(lo + 8);
            }
            // ---- stage B: 256 codes x 32 d ----
            {
                const float* lr = lut + (size_t)(kc * 256 + tid) * DIM + kd0;
                unsigned short hi[32], lo[32];
                #pragma unroll
                for (int q = 0; q < 8; ++q) {
                    float4 v = *(const float4*)(lr + q * 4);
                    float vv[4] = {v.x, v.y, v.z, v.w};
                    #pragma unroll
                    for (int e = 0; e < 4; ++e) {
                        unsigned short h = bf16_rne(vv[e]);
                        hi[q * 4 + e] = h;
                        lo[q * 4 + e] = bf16_rne(vv[e] - bf16_to_f(h));
                    }
                }
                char* rowb = bS + tid * 144;
                #pragma unroll
                for (int q = 0; q < 4; ++q) {
                    *(uint4*)(rowb + q * 16)      = pack8(hi + q * 8);
                    *(uint4*)(rowb + 64 + q * 16) = pack8(lo + q * 8);
                }
            }
            __syncthreads();
            // ---- MFMA ----
            short8v bhi[8], blo[8];
            #pragma unroll
            for (int ct = 0; ct < 8; ++ct) {
                const char* rb = bS + (wc * 128 + ct * 16 + l15) * 144 + l4 * 16;
                bhi[ct] = *(const short8v*)rb;
                blo[ct] = *(const short8v*)(rb + 64);
            }
            #pragma unroll
            for (int rt = 0; rt < 4; ++rt) {
                const char* ra = aS + (wr * 64 + rt * 16 + l15) * 144 + l4 * 16;
                short8v ahi = *(const short8v*)ra;
                short8v alo = *(const short8v*)(ra + 64);
                #pragma unroll
                for (int ct = 0; ct < 8; ++ct) {
                    acc[rt][ct] = __builtin_amdgcn_mfma_f32_16x16x32_bf16(ahi, bhi[ct], acc[rt][ct], 0, 0, 0);
                    acc[rt][ct] = __builtin_amdgcn_mfma_f32_16x16x32_bf16(ahi, blo[ct], acc[rt][ct], 0, 0, 0);
                    acc[rt][ct] = __builtin_amdgcn_mfma_f32_16x16x32_bf16(alo, bhi[ct], acc[rt][ct], 0, 0, 0);
                }
            }
        }
        // ---- fold this kc chunk: per-row best1/best2 over 256 codes ----
        #pragma unroll
        for (int rt = 0; rt < 4; ++rt) {
            #pragma unroll
            for (int r = 0; r < 4; ++r) {
                float v1 = 3.4e38f, v2 = 3.4e38f; int i1 = 0;
                #pragma unroll
                for (int ct = 0; ct < 8; ++ct) {
                    int code = kc * 256 + wc * 128 + ct * 16 + l15;
                    float dist = fmaf(-2.f, acc[rt][ct][r], c2s[code]);
                    if (dist < v1) { v2 = v1; v1 = dist; i1 = code; }
                    else if (dist < v2) v2 = dist;
                }
                #pragma unroll
                for (int off = 1; off < 16; off <<= 1) {
                    float ov1 = __shfl_xor(v1, off, 64);
                    int   oi1 = __shfl_xor(i1, off, 64);
                    float ov2 = __shfl_xor(v2, off, 64);
                    float nv2 = fminf(fmaxf(v1, ov1), fminf(v2, ov2));
                    if (ov1 < v1 || (ov1 == v1 && oi1 < i1)) { v1 = ov1; i1 = oi1; }
                    v2 = nv2;
                }
                if (l15 == 0) {
                    int row = wr * 64 + rt * 16 + l4 * 4 + r;
                    int s = kc * 2 + wc;
                    redv1[s][row] = v1; redi1[s][row] = i1; redv2[s][row] = v2;
                }
            }
        }
    }
    __syncthreads();

    float dist_part = 0.f;
    if (tid < QBM) {
        const int row = tid;
        float v1 = redv1[0][row]; int i1 = redi1[0][row]; float v2 = redv2[0][row];
        #pragma unroll
        for (int s = 1; s < 4; ++s) {
            float ov1 = redv1[s][row]; int oi1 = redi1[s][row]; float ov2 = redv2[s][row];
            float nv2 = fminf(fmaxf(v1, ov1), fminf(v2, ov2));
            if (ov1 < v1 || (ov1 == v1 && oi1 < i1)) { v1 = ov1; i1 = oi1; }
            v2 = nv2;
        }
        bool flag = (v2 - v1) <= MARGIN;
        out[OUT_Q_OFF + n0 + row] = flag ? -(float)(i1 + 1) : (float)i1;
        dist_part = v1;
    }

    float dv = dist_part;
    #pragma unroll
    for (int off = 32; off; off >>= 1) dv += __shfl_down(dv, off, 64);
    if (lane == 0) wsumd[wave] = dv;
    float xv = x2local;
    #pragma unroll
    for (int off = 32; off; off >>= 1) xv += __shfl_down(xv, off, 64);
    if (lane == 0) wsumx[wave] = xv;
    __syncthreads();
    if (tid == 0) {
        ws[WS_DIST + blk] = wsumd[0] + wsumd[1] + wsumd[2] + wsumd[3];
        ws[WS_X2 + blk]   = wsumx[0] + wsumx[1] + wsumx[2] + wsumx[3];
    }
}

// Exact fp32 re-check for flagged rows (q < 0): same arithmetic form as the R6-passing kernel.
__global__ void exact_kernel(const float* __restrict__ x, const float* __restrict__ lut,
                             float* __restrict__ out, const float* __restrict__ ws) {
    __shared__ float xr[DIM];
    __shared__ float rv[NT];
    __shared__ int   ri[NT];
    for (int row = blockIdx.x; row < N_ROWS; row += gridDim.x) {
        float qv = out[OUT_Q_OFF + row];
        if (qv >= 0.f) continue;       // uniform per block
        int b = row >> 10, hw = row & 1023;
        __syncthreads();
        xr[threadIdx.x] = x[(size_t)b * (DIM * HW) + (size_t)threadIdx.x * HW + hw];
        __syncthreads();
        float bv = 3.4e38f; int bi = 0;
        for (int k2 = 0; k2 < 2; ++k2) {
            int k = threadIdx.x + k2 * 256;
            const float* cr = lut + (size_t)k * DIM;
            float dot = 0.f;
            for (int d = 0; d < DIM; ++d) dot = fmaf(xr[d], cr[d], dot);
            float dist = fmaf(-2.f, dot, ws[k]);
            if (dist < bv || (dist == bv && k < bi)) { bv = dist; bi = k; }
        }
        rv[threadIdx.x] = bv; ri[threadIdx.x] = bi;
        __syncthreads();
        for (int s = 128; s; s >>= 1) {
            if (threadIdx.x < s) {
                float ov = rv[threadIdx.x + s]; int oi = ri[threadIdx.x + s];
                if (ov < rv[threadIdx.x] || (ov == rv[threadIdx.x] && oi < ri[threadIdx.x])) {
                    rv[threadIdx.x] = ov; ri[threadIdx.x] = oi;
                }
            }
            __syncthreads();
        }
        if (threadIdx.x == 0) out[OUT_Q_OFF + row] = (float)ri[0];
    }
}

__global__ void gather_kernel(const float* __restrict__ lut, float* __restrict__ out) {
    const long long stride = (long long)gridDim.x * NT;
    for (long long idx = (long long)blockIdx.x * NT + threadIdx.x;
         idx < 16777216LL; idx += stride) {
        int b  = (int)(idx >> 18);
        int d  = (int)(idx >> 10) & 255;
        int hw = (int)idx & 1023;
        int qi = (int)out[OUT_Q_OFF + (b << 10) + hw];
        out[idx] = lut[qi * DIM + d];
    }
}

__global__ void loss_kernel(float* __restrict__ out, const float* __restrict__ ws) {
    __shared__ float wsum[4];
    int tid = threadIdx.x;
    float s = 0.f;
    for (int i = tid; i < 1024; i += NT) s += ws[WS_DIST + i];
    #pragma unroll
    for (int off = 32; off; off >>= 1) s += __shfl_down(s, off, 64);
    if ((tid & 63) == 0) wsum[tid >> 6] = s;
    __syncthreads();
    if (tid == 0) {
        float total = wsum[0] + wsum[1] + wsum[2] + wsum[3];
        out[OUT_LOSS_OFF] = total * (1.25f / 16777216.f);
    }
}

extern "C" void kernel_launch(void* const* d_in, const int* in_sizes, int n_in,
                              void* d_out, int out_size, void* d_ws, size_t ws_size,
                              hipStream_t stream) {
    const float* x   = (const float*)d_in[0];
    const float* lut = (const float*)d_in[1];
    float* out = (float*)d_out;
    float* ws  = (float*)d_ws;

    c2_kernel<<<1, NT, 0, stream>>>(lut, ws);
    vq_kernel<<<NBLK, NT, 0, stream>>>(x, lut, out, ws);
    exact_kernel<<<4096, NT, 0, stream>>>(x, lut, out, ws);
    gather_kernel<<<8192, NT, 0, stream>>>(lut, out);
    loss_kernel<<<1, NT, 0, stream>>>(out, ws);
}

// Round 8
// 151.024 us; speedup vs baseline: 2.0452x; 2.0452x over previous
//
#include <hip/hip_runtime.h>

#define DIM     256
#define HW      1024
#define N_ROWS  65536
#define NT      512
#define QBM     128
#define NBLK    512
#define MARGIN  0.0625f

#define OUT_Q_OFF    16777216
#define OUT_LOSS_OFF 16842752

// ws: floats [0,512) c2 ; [512,1024) dist partials ; [1024,1536) x2 partials
// ints: [1536] flag count ; [2048, 67584) flagged-row list
// bytes: [524288, 1048576) lut bf16 hi/lo fragment-linear
#define WS_DIST   512
#define WS_X2     1024
#define WS_CNT_I  1536
#define WS_LIST_I 2048
#define WS_LUTBF_B 524288

typedef __attribute__((ext_vector_type(8))) short short8v;
typedef __attribute__((ext_vector_type(4))) float floatx4;

__device__ __forceinline__ unsigned short bf16_rne(float f) {
    unsigned int u = __float_as_uint(f);
    u += 0x7fffu + ((u >> 16) & 1u);
    return (unsigned short)(u >> 16);
}
__device__ __forceinline__ float bf16_to_f(unsigned short h) {
    return __uint_as_float(((unsigned int)h) << 16);
}
__device__ __forceinline__ uint4 pack8(const unsigned short* h) {
    uint4 u;
    u.x = (unsigned)h[0] | ((unsigned)h[1] << 16);
    u.y = (unsigned)h[2] | ((unsigned)h[3] << 16);
    u.z = (unsigned)h[4] | ((unsigned)h[5] << 16);
    u.w = (unsigned)h[6] | ((unsigned)h[7] << 16);
    return u;
}

__global__ void c2_kernel(const float* __restrict__ lut, float* __restrict__ ws) {
    if (threadIdx.x == 0) ((int*)ws)[WS_CNT_I] = 0;
    int t = threadIdx.x;
    for (int k = t; k < 512; k += 256) {
        const float4* row = (const float4*)(lut + (size_t)k * DIM);
        float s = 0.f;
        #pragma unroll 8
        for (int i = 0; i < DIM / 4; ++i) {
            float4 v = row[i];
            s += v.x * v.x + v.y * v.y + v.z * v.z + v.w * v.w;
        }
        ws[k] = s;
    }
}

// lut -> bf16 hi/lo, fragment-linear: [dc(8)][ctg(32)][level(2)][lane(64)]*16B
__global__ void lutprep_kernel(const float* __restrict__ lut, float* __restrict__ ws) {
    int g = blockIdx.x * 256 + threadIdx.x;    // 0..16383
    int lane = g & 63;
    int ctg  = (g >> 6) & 31;
    int dcg  = g >> 11;
    int code = ctg * 16 + (lane & 15);
    int d0   = dcg * 32 + (lane >> 4) * 8;
    const float* src = lut + (size_t)code * DIM + d0;
    unsigned short hi[8], lo[8];
    #pragma unroll
    for (int j = 0; j < 8; ++j) {
        float v = src[j];
        unsigned short h = bf16_rne(v);
        hi[j] = h;
        lo[j] = bf16_rne(v - bf16_to_f(h));
    }
    char* dst = (char*)ws + WS_LUTBF_B + (size_t)((dcg * 32 + ctg) * 2) * 1024 + lane * 16;
    *(uint4*)dst          = pack8(hi);
    *(uint4*)(dst + 1024) = pack8(lo);
}

__global__ __launch_bounds__(NT, 2) void vq_kernel(const float* __restrict__ x,
                                                   const float* __restrict__ lut,
                                                   float* __restrict__ out,
                                                   float* __restrict__ ws) {
    __shared__ uint4 aS4[1024];            // 16 KB: [level(2)][rt(8)][lane(64)]*16B
    __shared__ float c2s[512];
    __shared__ float redv1[4][QBM];
    __shared__ float redv2[4][QBM];
    __shared__ int   redi1[4][QBM];
    __shared__ int   qsh[QBM];
    __shared__ float wsumd[2];
    __shared__ float wsumx[8];

    char* aS = (char*)aS4;
    const char* lutbf = (const char*)ws + WS_LUTBF_B;

    const int tid = threadIdx.x;
    const int blk = blockIdx.x;
    const int n0  = blk * QBM;
    const int b   = n0 >> 10;
    const int hw0 = n0 & 1023;
    const float* xb = x + (size_t)b * (DIM * HW) + hw0;

    for (int k = tid; k < 512; k += NT) c2s[k] = ws[k];

    const int wave = tid >> 6;
    const int lane = tid & 63;
    const int l15  = lane & 15;
    const int l4   = lane >> 4;
    const int rg   = wave >> 2;    // row group: rows rg*64..+63
    const int cg   = wave & 3;     // code group: codes cg*128..+127

    // staging map
    const int srow   = tid & 127;
    const int schunk = tid >> 7;   // 0..3
    const int srt    = srow >> 4;
    const int slf    = schunk * 16 + (srow & 15);

    float x2local = 0.f;
    floatx4 acc[4][8];
    #pragma unroll
    for (int i = 0; i < 4; ++i)
        #pragma unroll
        for (int j = 0; j < 8; ++j) acc[i][j] = (floatx4)0.f;

    for (int dc = 0; dc < 8; ++dc) {
        __syncthreads();
        // ---- stage A: 128 rows x 32 d -> hi/lo bf16, fragment-linear ----
        {
            const float* src = xb + (size_t)(dc * 32 + schunk * 8) * HW + srow;
            unsigned short hi[8], lo[8];
            #pragma unroll
            for (int j = 0; j < 8; ++j) {
                float v = src[(size_t)j * HW];
                x2local = fmaf(v, v, x2local);
                unsigned short h = bf16_rne(v);
                hi[j] = h;
                lo[j] = bf16_rne(v - bf16_to_f(h));
            }
            *(uint4*)(aS + srt * 1024 + slf * 16)        = pack8(hi);
            *(uint4*)(aS + 8192 + srt * 1024 + slf * 16) = pack8(lo);
        }
        __syncthreads();
        // ---- compute ----
        short8v ah[4], al[4];
        #pragma unroll
        for (int rtl = 0; rtl < 4; ++rtl) {
            ah[rtl] = *(const short8v*)(aS + (rg * 4 + rtl) * 1024 + lane * 16);
            al[rtl] = *(const short8v*)(aS + 8192 + (rg * 4 + rtl) * 1024 + lane * 16);
        }
        #pragma unroll
        for (int ct = 0; ct < 8; ++ct) {
            const char* bp = lutbf + (size_t)((dc * 32 + cg * 8 + ct) * 2) * 1024 + lane * 16;
            short8v bh = *(const short8v*)bp;
            short8v bl = *(const short8v*)(bp + 1024);
            #pragma unroll
            for (int rtl = 0; rtl < 4; ++rtl) {
                acc[rtl][ct] = __builtin_amdgcn_mfma_f32_16x16x32_bf16(ah[rtl], bh, acc[rtl][ct], 0, 0, 0);
                acc[rtl][ct] = __builtin_amdgcn_mfma_f32_16x16x32_bf16(al[rtl], bh, acc[rtl][ct], 0, 0, 0);
                acc[rtl][ct] = __builtin_amdgcn_mfma_f32_16x16x32_bf16(ah[rtl], bl, acc[rtl][ct], 0, 0, 0);
            }
        }
    }

    // ---- per-row best1/best2 ----
    #pragma unroll
    for (int rtl = 0; rtl < 4; ++rtl) {
        #pragma unroll
        for (int r = 0; r < 4; ++r) {
            float v1 = 3.4e38f, v2 = 3.4e38f; int i1 = 0;
            #pragma unroll
            for (int ct = 0; ct < 8; ++ct) {
                int code = cg * 128 + ct * 16 + l15;
                float dist = fmaf(-2.f, acc[rtl][ct][r], c2s[code]);
                if (dist < v1) { v2 = v1; v1 = dist; i1 = code; }
                else if (dist < v2) v2 = dist;
            }
            #pragma unroll
            for (int off = 1; off < 16; off <<= 1) {
                float ov1 = __shfl_xor(v1, off, 64);
                int   oi1 = __shfl_xor(i1, off, 64);
                float ov2 = __shfl_xor(v2, off, 64);
                float nv2 = fminf(fmaxf(v1, ov1), fminf(v2, ov2));
                if (ov1 < v1 || (ov1 == v1 && oi1 < i1)) { v1 = ov1; i1 = oi1; }
                v2 = nv2;
            }
            if (l15 == 0) {
                int row = rg * 64 + rtl * 16 + l4 * 4 + r;
                redv1[cg][row] = v1; redi1[cg][row] = i1; redv2[cg][row] = v2;
            }
        }
    }
    __syncthreads();

    float dist_part = 0.f;
    if (tid < QBM) {
        const int row = tid;
        float v1 = redv1[0][row]; int i1 = redi1[0][row]; float v2 = redv2[0][row];
        #pragma unroll
        for (int s = 1; s < 4; ++s) {
            float ov1 = redv1[s][row]; int oi1 = redi1[s][row]; float ov2 = redv2[s][row];
            float nv2 = fminf(fmaxf(v1, ov1), fminf(v2, ov2));
            if (ov1 < v1 || (ov1 == v1 && oi1 < i1)) { v1 = ov1; i1 = oi1; }
            v2 = nv2;
        }
        qsh[row] = i1;
        out[OUT_Q_OFF + n0 + row] = (float)i1;
        if (v2 - v1 <= MARGIN) {
            int idx = atomicAdd((int*)ws + WS_CNT_I, 1);
            ((int*)ws)[WS_LIST_I + idx] = n0 + row;
        }
        dist_part = v1;
    }

    // deterministic partial sums
    float dv = dist_part;
    #pragma unroll
    for (int off = 32; off; off >>= 1) dv += __shfl_down(dv, off, 64);
    if (lane == 0 && wave < 2) wsumd[wave] = dv;
    float xv = x2local;
    #pragma unroll
    for (int off = 32; off; off >>= 1) xv += __shfl_down(xv, off, 64);
    if (lane == 0) wsumx[wave] = xv;
    __syncthreads();
    if (tid == 0) {
        float xs = 0.f;
        #pragma unroll
        for (int w = 0; w < 8; ++w) xs += wsumx[w];
        ws[WS_DIST + blk] = wsumd[0] + wsumd[1];
        ws[WS_X2 + blk]   = xs;
    }

    // ---- x_e write (approx q; exact pass fixes flagged rows) ----
    {
        const int row = tid & 127;
        const int dg  = tid >> 7;      // 0..3 -> d range dg*64..+63
        const int q   = qsh[row];
        const float* crow = lut + (size_t)q * DIM;
        float* ob = out + (size_t)b * (DIM * HW) + hw0 + row;
        #pragma unroll 4
        for (int i = 0; i < 16; ++i) {
            int d0 = dg * 64 + i * 4;
            float4 c = *(const float4*)(crow + d0);
            ob[(size_t)(d0 + 0) * HW] = c.x;
            ob[(size_t)(d0 + 1) * HW] = c.y;
            ob[(size_t)(d0 + 2) * HW] = c.z;
            ob[(size_t)(d0 + 3) * HW] = c.w;
        }
    }
}

// exact fp32 recheck of flagged rows (sequential-fmaf form, matches np-passing R6/R7)
__global__ void exact_kernel(const float* __restrict__ x, const float* __restrict__ lut,
                             float* __restrict__ out, const float* __restrict__ ws) {
    __shared__ float xr[DIM];
    __shared__ float rv[256];
    __shared__ int   ri[256];
    const int cnt = ((const int*)ws)[WS_CNT_I];
    const int* list = (const int*)ws + WS_LIST_I;
    const int tid = threadIdx.x;
    for (int ii = blockIdx.x; ii < cnt; ii += gridDim.x) {
        const int row = list[ii];
        const int b = row >> 10, hw = row & 1023;
        __syncthreads();
        xr[tid] = x[(size_t)b * (DIM * HW) + (size_t)tid * HW + hw];
        __syncthreads();
        float bv = 3.4e38f; int bi = 0;
        #pragma unroll
        for (int k2 = 0; k2 < 2; ++k2) {
            int k = tid + k2 * 256;
            const float* cr = lut + (size_t)k * DIM;
            float dot = 0.f;
            for (int d = 0; d < DIM; ++d) dot = fmaf(xr[d], cr[d], dot);
            float dist = fmaf(-2.f, dot, ws[k]);
            if (dist < bv || (dist == bv && k < bi)) { bv = dist; bi = k; }
        }
        rv[tid] = bv; ri[tid] = bi;
        __syncthreads();
        for (int s = 128; s; s >>= 1) {
            if (tid < s) {
                float ov = rv[tid + s]; int oi = ri[tid + s];
                if (ov < rv[tid] || (ov == rv[tid] && oi < ri[tid])) {
                    rv[tid] = ov; ri[tid] = oi;
                }
            }
            __syncthreads();
        }
        const int q = ri[0];
        if (tid == 0) out[OUT_Q_OFF + row] = (float)q;
        out[(size_t)b * (DIM * HW) + (size_t)tid * HW + hw] = lut[(size_t)q * DIM + tid];
    }
}

__global__ void loss_kernel(float* __restrict__ out, const float* __restrict__ ws) {
    __shared__ float wsum[4];
    int tid = threadIdx.x;
    float s = 0.f;
    for (int i = tid; i < 1024; i += 256) s += ws[WS_DIST + i];
    #pragma unroll
    for (int off = 32; off; off >>= 1) s += __shfl_down(s, off, 64);
    if ((tid & 63) == 0) wsum[tid >> 6] = s;
    __syncthreads();
    if (tid == 0) {
        float total = wsum[0] + wsum[1] + wsum[2] + wsum[3];
        out[OUT_LOSS_OFF] = total * (1.25f / 16777216.f);
    }
}

extern "C" void kernel_launch(void* const* d_in, const int* in_sizes, int n_in,
                              void* d_out, int out_size, void* d_ws, size_t ws_size,
                              hipStream_t stream) {
    const float* x   = (const float*)d_in[0];
    const float* lut = (const float*)d_in[1];
    float* out = (float*)d_out;
    float* ws  = (float*)d_ws;

    c2_kernel<<<1, 256, 0, stream>>>(lut, ws);
    lutprep_kernel<<<64, 256, 0, stream>>>(lut, ws);
    vq_kernel<<<NBLK, NT, 0, stream>>>(x, lut, out, ws);
    exact_kernel<<<2048, 256, 0, stream>>>(x, lut, out, ws);
    loss_kernel<<<1, 256, 0, stream>>>(out, ws);
}

// Round 9
// 147.412 us; speedup vs baseline: 2.0953x; 1.0245x over previous
//
#include <hip/hip_runtime.h>

#define DIM     256
#define HW      1024
#define N_ROWS  65536
#define NT      512
#define QBM     128
#define NBLK    512
#define MARGIN  0.0625f

#define OUT_Q_OFF    16777216
#define OUT_LOSS_OFF 16842752

// ws: floats [0,512) c2 ; [512,1024) dist partials ; [1024,1536) x2 partials
// ints: [1536] flag count ; [2048, 67584) flagged-row list
// bytes: [524288, 1048576) lut bf16 hi/lo fragment-linear
#define WS_DIST   512
#define WS_X2     1024
#define WS_CNT_I  1536
#define WS_LIST_I 2048
#define WS_LUTBF_B 524288

typedef __attribute__((ext_vector_type(8))) short short8v;
typedef __attribute__((ext_vector_type(4))) float floatx4;

__device__ __forceinline__ unsigned short bf16_rne(float f) {
    unsigned int u = __float_as_uint(f);
    u += 0x7fffu + ((u >> 16) & 1u);
    return (unsigned short)(u >> 16);
}
__device__ __forceinline__ float bf16_to_f(unsigned short h) {
    return __uint_as_float(((unsigned int)h) << 16);
}
__device__ __forceinline__ uint4 pack8(const unsigned short* h) {
    uint4 u;
    u.x = (unsigned)h[0] | ((unsigned)h[1] << 16);
    u.y = (unsigned)h[2] | ((unsigned)h[3] << 16);
    u.z = (unsigned)h[4] | ((unsigned)h[5] << 16);
    u.w = (unsigned)h[6] | ((unsigned)h[7] << 16);
    return u;
}

__global__ void c2_kernel(const float* __restrict__ lut, float* __restrict__ ws) {
    if (threadIdx.x == 0) ((int*)ws)[WS_CNT_I] = 0;
    int t = threadIdx.x;
    for (int k = t; k < 512; k += 256) {
        const float4* row = (const float4*)(lut + (size_t)k * DIM);
        float s = 0.f;
        #pragma unroll 8
        for (int i = 0; i < DIM / 4; ++i) {
            float4 v = row[i];
            s += v.x * v.x + v.y * v.y + v.z * v.z + v.w * v.w;
        }
        ws[k] = s;
    }
}

// lut -> bf16 hi/lo, fragment-linear: [dc(8)][ctg(32)][level(2)][lane(64)]*16B
__global__ void lutprep_kernel(const float* __restrict__ lut, float* __restrict__ ws) {
    int g = blockIdx.x * 256 + threadIdx.x;    // 0..16383
    int lane = g & 63;
    int ctg  = (g >> 6) & 31;
    int dcg  = g >> 11;
    int code = ctg * 16 + (lane & 15);
    int d0   = dcg * 32 + (lane >> 4) * 8;
    const float* src = lut + (size_t)code * DIM + d0;
    unsigned short hi[8], lo[8];
    #pragma unroll
    for (int j = 0; j < 8; ++j) {
        float v = src[j];
        unsigned short h = bf16_rne(v);
        hi[j] = h;
        lo[j] = bf16_rne(v - bf16_to_f(h));
    }
    char* dst = (char*)ws + WS_LUTBF_B + (size_t)((dcg * 32 + ctg) * 2) * 1024 + lane * 16;
    *(uint4*)dst          = pack8(hi);
    *(uint4*)(dst + 1024) = pack8(lo);
}

__global__ __launch_bounds__(NT, 2) void vq_kernel(const float* __restrict__ x,
                                                   const float* __restrict__ lut,
                                                   float* __restrict__ out,
                                                   float* __restrict__ ws) {
    __shared__ char aS[2][16384];          // 32 KB double-buffered A
    __shared__ float c2s[512];
    __shared__ float redv1[4][QBM];
    __shared__ float redv2[4][QBM];
    __shared__ int   redi1[4][QBM];
    __shared__ int   qsh[QBM];
    __shared__ float wsumd[2];
    __shared__ float wsumx[8];

    const char* lutbf = (const char*)ws + WS_LUTBF_B;

    const int tid = threadIdx.x;
    const int blk = blockIdx.x;
    const int n0  = blk * QBM;
    const int b   = n0 >> 10;
    const int hw0 = n0 & 1023;
    const float* xb = x + (size_t)b * (DIM * HW) + hw0;

    for (int k = tid; k < 512; k += NT) c2s[k] = ws[k];

    const int wave = tid >> 6;
    const int lane = tid & 63;
    const int l15  = lane & 15;
    const int l4   = lane >> 4;
    const int rg   = wave >> 2;    // row group: rows rg*64..+63
    const int cg   = wave & 3;     // code group: codes cg*128..+127

    // staging map
    const int srow   = tid & 127;
    const int schunk = tid >> 7;   // 0..3
    const int srt    = srow >> 4;
    const int slf    = schunk * 16 + (srow & 15);
    char* awr_hi0 = &aS[0][srt * 1024 + slf * 16];
    char* awr_hi1 = &aS[1][srt * 1024 + slf * 16];

    float x2local = 0.f;
    floatx4 acc[4][8];
    #pragma unroll
    for (int i = 0; i < 4; ++i)
        #pragma unroll
        for (int j = 0; j < 8; ++j) acc[i][j] = (floatx4)0.f;

    // ---- prologue: stage dc=0 into buf 0 ----
    {
        const float* src = xb + (size_t)(schunk * 8) * HW + srow;
        unsigned short hi[8], lo[8];
        #pragma unroll
        for (int j = 0; j < 8; ++j) {
            float v = src[(size_t)j * HW];
            x2local = fmaf(v, v, x2local);
            unsigned short h = bf16_rne(v);
            hi[j] = h;
            lo[j] = bf16_rne(v - bf16_to_f(h));
        }
        *(uint4*)awr_hi0          = pack8(hi);
        *(uint4*)(awr_hi0 + 8192) = pack8(lo);
    }
    __syncthreads();

    for (int dc = 0; dc < 8; ++dc) {
        const int cur = dc & 1;
        // ---- prefetch next dc's x into registers (T14 issue-early) ----
        float xn[8];
        if (dc < 7) {
            const float* src = xb + (size_t)((dc + 1) * 32 + schunk * 8) * HW + srow;
            #pragma unroll
            for (int j = 0; j < 8; ++j) xn[j] = src[(size_t)j * HW];
        }
        // ---- A frags from LDS ----
        short8v ah[4], al[4];
        #pragma unroll
        for (int rtl = 0; rtl < 4; ++rtl) {
            const char* ra = &aS[cur][(rg * 4 + rtl) * 1024 + lane * 16];
            ah[rtl] = *(const short8v*)ra;
            al[rtl] = *(const short8v*)(ra + 8192);
        }
        // ---- B frags from global (L2) ----
        short8v bh[8], bl[8];
        #pragma unroll
        for (int ct = 0; ct < 8; ++ct) {
            const char* bp = lutbf + (size_t)((dc * 32 + cg * 8 + ct) * 2) * 1024 + lane * 16;
            bh[ct] = *(const short8v*)bp;
            bl[ct] = *(const short8v*)(bp + 1024);
        }
        // ---- MFMAs (same order as R8 -> bitwise-identical acc) ----
        #pragma unroll
        for (int ct = 0; ct < 8; ++ct) {
            #pragma unroll
            for (int rtl = 0; rtl < 4; ++rtl) {
                acc[rtl][ct] = __builtin_amdgcn_mfma_f32_16x16x32_bf16(ah[rtl], bh[ct], acc[rtl][ct], 0, 0, 0);
                acc[rtl][ct] = __builtin_amdgcn_mfma_f32_16x16x32_bf16(al[rtl], bh[ct], acc[rtl][ct], 0, 0, 0);
                acc[rtl][ct] = __builtin_amdgcn_mfma_f32_16x16x32_bf16(ah[rtl], bl[ct], acc[rtl][ct], 0, 0, 0);
            }
        }
        // ---- convert + write next buffer (T14 write-late), then publish ----
        if (dc < 7) {
            unsigned short hi[8], lo[8];
            #pragma unroll
            for (int j = 0; j < 8; ++j) {
                float v = xn[j];
                x2local = fmaf(v, v, x2local);
                unsigned short h = bf16_rne(v);
                hi[j] = h;
                lo[j] = bf16_rne(v - bf16_to_f(h));
            }
            char* wr = cur ? awr_hi0 : awr_hi1;
            *(uint4*)wr          = pack8(hi);
            *(uint4*)(wr + 8192) = pack8(lo);
            __syncthreads();
        }
    }

    // ---- per-row best1/best2 (unchanged) ----
    #pragma unroll
    for (int rtl = 0; rtl < 4; ++rtl) {
        #pragma unroll
        for (int r = 0; r < 4; ++r) {
            float v1 = 3.4e38f, v2 = 3.4e38f; int i1 = 0;
            #pragma unroll
            for (int ct = 0; ct < 8; ++ct) {
                int code = cg * 128 + ct * 16 + l15;
                float dist = fmaf(-2.f, acc[rtl][ct][r], c2s[code]);
                if (dist < v1) { v2 = v1; v1 = dist; i1 = code; }
                else if (dist < v2) v2 = dist;
            }
            #pragma unroll
            for (int off = 1; off < 16; off <<= 1) {
                float ov1 = __shfl_xor(v1, off, 64);
                int   oi1 = __shfl_xor(i1, off, 64);
                float ov2 = __shfl_xor(v2, off, 64);
                float nv2 = fminf(fmaxf(v1, ov1), fminf(v2, ov2));
                if (ov1 < v1 || (ov1 == v1 && oi1 < i1)) { v1 = ov1; i1 = oi1; }
                v2 = nv2;
            }
            if (l15 == 0) {
                int row = rg * 64 + rtl * 16 + l4 * 4 + r;
                redv1[cg][row] = v1; redi1[cg][row] = i1; redv2[cg][row] = v2;
            }
        }
    }
    __syncthreads();

    float dist_part = 0.f;
    if (tid < QBM) {
        const int row = tid;
        float v1 = redv1[0][row]; int i1 = redi1[0][row]; float v2 = redv2[0][row];
        #pragma unroll
        for (int s = 1; s < 4; ++s) {
            float ov1 = redv1[s][row]; int oi1 = redi1[s][row]; float ov2 = redv2[s][row];
            float nv2 = fminf(fmaxf(v1, ov1), fminf(v2, ov2));
            if (ov1 < v1 || (ov1 == v1 && oi1 < i1)) { v1 = ov1; i1 = oi1; }
            v2 = nv2;
        }
        qsh[row] = i1;
        out[OUT_Q_OFF + n0 + row] = (float)i1;
        if (v2 - v1 <= MARGIN) {
            int idx = atomicAdd((int*)ws + WS_CNT_I, 1);
            ((int*)ws)[WS_LIST_I + idx] = n0 + row;
        }
        dist_part = v1;
    }

    float dv = dist_part;
    #pragma unroll
    for (int off = 32; off; off >>= 1) dv += __shfl_down(dv, off, 64);
    if (lane == 0 && wave < 2) wsumd[wave] = dv;
    float xv = x2local;
    #pragma unroll
    for (int off = 32; off; off >>= 1) xv += __shfl_down(xv, off, 64);
    if (lane == 0) wsumx[wave] = xv;
    __syncthreads();
    if (tid == 0) {
        float xs = 0.f;
        #pragma unroll
        for (int w = 0; w < 8; ++w) xs += wsumx[w];
        ws[WS_DIST + blk] = wsumd[0] + wsumd[1];
        ws[WS_X2 + blk]   = xs;
    }

    // ---- x_e write (approx q; exact pass fixes flagged rows) ----
    {
        const int row = tid & 127;
        const int dg  = tid >> 7;
        const int q   = qsh[row];
        const float* crow = lut + (size_t)q * DIM;
        float* ob = out + (size_t)b * (DIM * HW) + hw0 + row;
        #pragma unroll 4
        for (int i = 0; i < 16; ++i) {
            int d0 = dg * 64 + i * 4;
            float4 c = *(const float4*)(crow + d0);
            ob[(size_t)(d0 + 0) * HW] = c.x;
            ob[(size_t)(d0 + 1) * HW] = c.y;
            ob[(size_t)(d0 + 2) * HW] = c.z;
            ob[(size_t)(d0 + 3) * HW] = c.w;
        }
    }
}

// exact fp32 recheck of flagged rows (sequential-fmaf form, matches np-passing R6/R7)
__global__ void exact_kernel(const float* __restrict__ x, const float* __restrict__ lut,
                             float* __restrict__ out, const float* __restrict__ ws) {
    __shared__ float xr[DIM];
    __shared__ float rv[256];
    __shared__ int   ri[256];
    const int cnt = ((const int*)ws)[WS_CNT_I];
    const int* list = (const int*)ws + WS_LIST_I;
    const int tid = threadIdx.x;
    for (int ii = blockIdx.x; ii < cnt; ii += gridDim.x) {
        const int row = list[ii];
        const int b = row >> 10, hw = row & 1023;
        __syncthreads();
        xr[tid] = x[(size_t)b * (DIM * HW) + (size_t)tid * HW + hw];
        __syncthreads();
        float bv = 3.4e38f; int bi = 0;
        #pragma unroll
        for (int k2 = 0; k2 < 2; ++k2) {
            int k = tid + k2 * 256;
            const float* cr = lut + (size_t)k * DIM;
            float dot = 0.f;
            for (int d = 0; d < DIM; ++d) dot = fmaf(xr[d], cr[d], dot);
            float dist = fmaf(-2.f, dot, ws[k]);
            if (dist < bv || (dist == bv && k < bi)) { bv = dist; bi = k; }
        }
        rv[tid] = bv; ri[tid] = bi;
        __syncthreads();
        for (int s = 128; s; s >>= 1) {
            if (tid < s) {
                float ov = rv[tid + s]; int oi = ri[tid + s];
                if (ov < rv[tid] || (ov == rv[tid] && oi < ri[tid])) {
                    rv[tid] = ov; ri[tid] = oi;
                }
            }
            __syncthreads();
        }
        const int q = ri[0];
        if (tid == 0) out[OUT_Q_OFF + row] = (float)q;
        out[(size_t)b * (DIM * HW) + (size_t)tid * HW + hw] = lut[(size_t)q * DIM + tid];
    }
}

__global__ void loss_kernel(float* __restrict__ out, const float* __restrict__ ws) {
    __shared__ float wsum[4];
    int tid = threadIdx.x;
    float s = 0.f;
    for (int i = tid; i < 1024; i += 256) s += ws[WS_DIST + i];
    #pragma unroll
    for (int off = 32; off; off >>= 1) s += __shfl_down(s, off, 64);
    if ((tid & 63) == 0) wsum[tid >> 6] = s;
    __syncthreads();
    if (tid == 0) {
        float total = wsum[0] + wsum[1] + wsum[2] + wsum[3];
        out[OUT_LOSS_OFF] = total * (1.25f / 16777216.f);
    }
}

extern "C" void kernel_launch(void* const* d_in, const int* in_sizes, int n_in,
                              void* d_out, int out_size, void* d_ws, size_t ws_size,
                              hipStream_t stream) {
    const float* x   = (const float*)d_in[0];
    const float* lut = (const float*)d_in[1];
    float* out = (float*)d_out;
    float* ws  = (float*)d_ws;

    c2_kernel<<<1, 256, 0, stream>>>(lut, ws);
    lutprep_kernel<<<64, 256, 0, stream>>>(lut, ws);
    vq_kernel<<<NBLK, NT, 0, stream>>>(x, lut, out, ws);
    exact_kernel<<<2048, 256, 0, stream>>>(x, lut, out, ws);
    loss_kernel<<<1, 256, 0, stream>>>(out, ws);
}

// Round 11
// 145.613 us; speedup vs baseline: 2.1212x; 1.0124x over previous
//
#include <hip/hip_runtime.h>

#define DIM     256
#define HW      1024
#define N_ROWS  65536
#define NT      512
#define QBM     128
#define NBLK    512
#define MARGIN  0.0625f

#define OUT_Q_OFF    16777216
#define OUT_LOSS_OFF 16842752

// ws: floats [0,512) c2 ; [512,1024) dist partials ; [1024,1536) x2 partials
// ints: [1536] flag count ; [2048, 67584) flagged-row list
// bytes: [524288, 1048576) lut bf16 hi/lo fragment-linear
#define WS_DIST   512
#define WS_X2     1024
#define WS_CNT_I  1536
#define WS_LIST_I 2048
#define WS_LUTBF_B 524288

#define VQ_LDS (147456)   // 2*64KB B dbuf + 16KB A

typedef __attribute__((ext_vector_type(8))) short short8v;
typedef __attribute__((ext_vector_type(4))) float floatx4;

#define GLOAD_LDS16(gaddr, laddr) \
    __builtin_amdgcn_global_load_lds((const __attribute__((address_space(1))) unsigned int*)(gaddr), \
                                     (__attribute__((address_space(3))) unsigned int*)(laddr), 16, 0, 0)

__device__ __forceinline__ unsigned short bf16_rne(float f) {
    unsigned int u = __float_as_uint(f);
    u += 0x7fffu + ((u >> 16) & 1u);
    return (unsigned short)(u >> 16);
}
__device__ __forceinline__ float bf16_to_f(unsigned short h) {
    return __uint_as_float(((unsigned int)h) << 16);
}
__device__ __forceinline__ uint4 pack8(const unsigned short* h) {
    uint4 u;
    u.x = (unsigned)h[0] | ((unsigned)h[1] << 16);
    u.y = (unsigned)h[2] | ((unsigned)h[3] << 16);
    u.z = (unsigned)h[4] | ((unsigned)h[5] << 16);
    u.w = (unsigned)h[6] | ((unsigned)h[7] << 16);
    return u;
}

__global__ void c2_kernel(const float* __restrict__ lut, float* __restrict__ ws) {
    if (threadIdx.x == 0) ((int*)ws)[WS_CNT_I] = 0;
    int t = threadIdx.x;
    for (int k = t; k < 512; k += 256) {
        const float4* row = (const float4*)(lut + (size_t)k * DIM);
        float s = 0.f;
        #pragma unroll 8
        for (int i = 0; i < DIM / 4; ++i) {
            float4 v = row[i];
            s += v.x * v.x + v.y * v.y + v.z * v.z + v.w * v.w;
        }
        ws[k] = s;
    }
}

// lut -> bf16 hi/lo, fragment-linear: [dc(8)][ctg(32)][level(2)][lane(64)]*16B
__global__ void lutprep_kernel(const float* __restrict__ lut, float* __restrict__ ws) {
    int g = blockIdx.x * 256 + threadIdx.x;    // 0..16383
    int lane = g & 63;
    int ctg  = (g >> 6) & 31;
    int dcg  = g >> 11;
    int code = ctg * 16 + (lane & 15);
    int d0   = dcg * 32 + (lane >> 4) * 8;
    const float* src = lut + (size_t)code * DIM + d0;
    unsigned short hi[8], lo[8];
    #pragma unroll
    for (int j = 0; j < 8; ++j) {
        float v = src[j];
        unsigned short h = bf16_rne(v);
        hi[j] = h;
        lo[j] = bf16_rne(v - bf16_to_f(h));
    }
    char* dst = (char*)ws + WS_LUTBF_B + (size_t)((dcg * 32 + ctg) * 2) * 1024 + lane * 16;
    *(uint4*)dst          = pack8(hi);
    *(uint4*)(dst + 1024) = pack8(lo);
}

__global__ __launch_bounds__(NT, 2) void vq_kernel(const float* __restrict__ x,
                                                   const float* __restrict__ lut,
                                                   float* __restrict__ out,
                                                   float* __restrict__ ws) {
    extern __shared__ char smem[];
    char* abuf = smem + 131072;                 // A single buffer, 16 KB

    const char* lutbf = (const char*)ws + WS_LUTBF_B;

    const int tid = threadIdx.x;
    const int blk = blockIdx.x;
    const int n0  = blk * QBM;
    const int b   = n0 >> 10;
    const int hw0 = n0 & 1023;
    const float* xb = x + (size_t)b * (DIM * HW) + hw0;

    const int wave = tid >> 6;
    const int lane = tid & 63;
    const int l15  = lane & 15;
    const int l4   = lane >> 4;
    const int rg   = wave >> 2;    // row group: rows rg*64..+63
    const int cg   = wave & 3;     // code group: codes cg*128..+127

    // c2 values this thread folds with (code = cg*128 + ct*16 + l15)
    float c2reg[8];
    #pragma unroll
    for (int ct = 0; ct < 8; ++ct) c2reg[ct] = ws[cg * 128 + ct * 16 + l15];

    // staging map for A
    const int srow   = tid & 127;
    const int schunk = tid >> 7;   // 0..3
    const int srt    = srow >> 4;
    const int slf    = schunk * 16 + (srow & 15);
    char* awr = abuf + srt * 1024 + slf * 16;

    float x2local = 0.f;
    floatx4 acc[4][8];
    #pragma unroll
    for (int i = 0; i < 4; ++i)
        #pragma unroll
        for (int j = 0; j < 8; ++j) acc[i][j] = (floatx4)0.f;

    // ---- prologue: DMA B[0], stage A[0] ----
    {
        #pragma unroll
        for (int c = 0; c < 8; ++c) {
            int u = c * 8 + wave;
            GLOAD_LDS16(lutbf + (size_t)u * 1024 + lane * 16, smem + u * 1024);
        }
        const float* src = xb + (size_t)(schunk * 8) * HW + srow;
        unsigned short hi[8], lo[8];
        #pragma unroll
        for (int j = 0; j < 8; ++j) {
            float v = src[(size_t)j * HW];
            x2local = fmaf(v, v, x2local);
            unsigned short h = bf16_rne(v);
            hi[j] = h;
            lo[j] = bf16_rne(v - bf16_to_f(h));
        }
        *(uint4*)awr          = pack8(hi);
        *(uint4*)(awr + 8192) = pack8(lo);
    }
    __syncthreads();   // drains DMA + publishes A[0]

    for (int dc = 0; dc < 8; ++dc) {
        const int cur = dc & 1;
        char* bcur = smem + cur * 65536;
        // ---- issue DMA for B[dc+1] + x prefetch ----
        float xn[8];
        if (dc < 7) {
            char* bnxt = smem + (cur ^ 1) * 65536;
            const char* bsrc = lutbf + (size_t)(dc + 1) * 65536;
            #pragma unroll
            for (int c = 0; c < 8; ++c) {
                int u = c * 8 + wave;
                GLOAD_LDS16(bsrc + (size_t)u * 1024 + lane * 16, bnxt + u * 1024);
            }
            const float* src = xb + (size_t)((dc + 1) * 32 + schunk * 8) * HW + srow;
            #pragma unroll
            for (int j = 0; j < 8; ++j) xn[j] = src[(size_t)j * HW];
        }
        // ---- A frags from LDS ----
        short8v ah[4], al[4];
        #pragma unroll
        for (int rtl = 0; rtl < 4; ++rtl) {
            const char* ra = abuf + (rg * 4 + rtl) * 1024 + lane * 16;
            ah[rtl] = *(const short8v*)ra;
            al[rtl] = *(const short8v*)(ra + 8192);
        }
        // ---- B frags from LDS ----
        short8v bh[8], bl[8];
        #pragma unroll
        for (int ct = 0; ct < 8; ++ct) {
            const char* bp = bcur + (size_t)((cg * 8 + ct) * 2) * 1024 + lane * 16;
            bh[ct] = *(const short8v*)bp;
            bl[ct] = *(const short8v*)(bp + 1024);
        }
        // ---- MFMAs: level-outer (independent within level; per-acc order hh,lh,hl kept) ----
        #pragma unroll
        for (int ct = 0; ct < 8; ++ct)
            #pragma unroll
            for (int rtl = 0; rtl < 4; ++rtl)
                acc[rtl][ct] = __builtin_amdgcn_mfma_f32_16x16x32_bf16(ah[rtl], bh[ct], acc[rtl][ct], 0, 0, 0);
        #pragma unroll
        for (int ct = 0; ct < 8; ++ct)
            #pragma unroll
            for (int rtl = 0; rtl < 4; ++rtl)
                acc[rtl][ct] = __builtin_amdgcn_mfma_f32_16x16x32_bf16(al[rtl], bh[ct], acc[rtl][ct], 0, 0, 0);
        #pragma unroll
        for (int ct = 0; ct < 8; ++ct)
            #pragma unroll
            for (int rtl = 0; rtl < 4; ++rtl)
                acc[rtl][ct] = __builtin_amdgcn_mfma_f32_16x16x32_bf16(ah[rtl], bl[ct], acc[rtl][ct], 0, 0, 0);
        // ---- publish A[dc+1] ----
        if (dc < 7) {
            __builtin_amdgcn_s_barrier();   // A[dc] reads complete block-wide (no drain needed)
            unsigned short hi[8], lo[8];
            #pragma unroll
            for (int j = 0; j < 8; ++j) {
                float v = xn[j];
                x2local = fmaf(v, v, x2local);
                unsigned short h = bf16_rne(v);
                hi[j] = h;
                lo[j] = bf16_rne(v - bf16_to_f(h));
            }
            *(uint4*)awr          = pack8(hi);
            *(uint4*)(awr + 8192) = pack8(lo);
            __syncthreads();   // full drain: A writes visible + B[dc+1] DMA complete
        }
    }
    __syncthreads();   // all A reads done before overlaying red arrays onto abuf

    // overlays in abuf (A data dead)
    float (*redv1)[QBM] = (float (*)[QBM])(abuf);
    float (*redv2)[QBM] = (float (*)[QBM])(abuf + 2048);
    int   (*redi1)[QBM] = (int (*)[QBM])(abuf + 4096);
    int*   qsh   = (int*)(abuf + 6144);
    float* wsumd = (float*)(abuf + 6656);
    float* wsumx = (float*)(abuf + 6688);

    // ---- per-row best1/best2 ----
    #pragma unroll
    for (int rtl = 0; rtl < 4; ++rtl) {
        #pragma unroll
        for (int r = 0; r < 4; ++r) {
            float v1 = 3.4e38f, v2 = 3.4e38f; int i1 = 0;
            #pragma unroll
            for (int ct = 0; ct < 8; ++ct) {
                int code = cg * 128 + ct * 16 + l15;
                float dist = fmaf(-2.f, acc[rtl][ct][r], c2reg[ct]);
                if (dist < v1) { v2 = v1; v1 = dist; i1 = code; }
                else if (dist < v2) v2 = dist;
            }
            #pragma unroll
            for (int off = 1; off < 16; off <<= 1) {
                float ov1 = __shfl_xor(v1, off, 64);
                int   oi1 = __shfl_xor(i1, off, 64);
                float ov2 = __shfl_xor(v2, off, 64);
                float nv2 = fminf(fmaxf(v1, ov1), fminf(v2, ov2));
                if (ov1 < v1 || (ov1 == v1 && oi1 < i1)) { v1 = ov1; i1 = oi1; }
                v2 = nv2;
            }
            if (l15 == 0) {
                int row = rg * 64 + rtl * 16 + l4 * 4 + r;
                redv1[cg][row] = v1; redi1[cg][row] = i1; redv2[cg][row] = v2;
            }
        }
    }
    __syncthreads();

    float dist_part = 0.f;
    if (tid < QBM) {
        const int row = tid;
        float v1 = redv1[0][row]; int i1 = redi1[0][row]; float v2 = redv2[0][row];
        #pragma unroll
        for (int s = 1; s < 4; ++s) {
            float ov1 = redv1[s][row]; int oi1 = redi1[s][row]; float ov2 = redv2[s][row];
            float nv2 = fminf(fmaxf(v1, ov1), fminf(v2, ov2));
            if (ov1 < v1 || (ov1 == v1 && oi1 < i1)) { v1 = ov1; i1 = oi1; }
            v2 = nv2;
        }
        qsh[row] = i1;
        out[OUT_Q_OFF + n0 + row] = (float)i1;
        if (v2 - v1 <= MARGIN) {
            int idx = atomicAdd((int*)ws + WS_CNT_I, 1);
            ((int*)ws)[WS_LIST_I + idx] = n0 + row;
        }
        dist_part = v1;
    }

    float dv = dist_part;
    #pragma unroll
    for (int off = 32; off; off >>= 1) dv += __shfl_down(dv, off, 64);
    if (lane == 0 && wave < 2) wsumd[wave] = dv;
    float xv = x2local;
    #pragma unroll
    for (int off = 32; off; off >>= 1) xv += __shfl_down(xv, off, 64);
    if (lane == 0) wsumx[wave] = xv;
    __syncthreads();
    if (tid == 0) {
        float xs = 0.f;
        #pragma unroll
        for (int w = 0; w < 8; ++w) xs += wsumx[w];
        ws[WS_DIST + blk] = wsumd[0] + wsumd[1];
        ws[WS_X2 + blk]   = xs;
    }

    // ---- x_e write (approx q; exact pass fixes flagged rows) ----
    {
        const int row = tid & 127;
        const int dg  = tid >> 7;
        const int q   = qsh[row];
        const float* crow = lut + (size_t)q * DIM;
        float* ob = out + (size_t)b * (DIM * HW) + hw0 + row;
        #pragma unroll 4
        for (int i = 0; i < 16; ++i) {
            int d0 = dg * 64 + i * 4;
            float4 c = *(const float4*)(crow + d0);
            ob[(size_t)(d0 + 0) * HW] = c.x;
            ob[(size_t)(d0 + 1) * HW] = c.y;
            ob[(size_t)(d0 + 2) * HW] = c.z;
            ob[(size_t)(d0 + 3) * HW] = c.w;
        }
    }
}

// exact fp32 recheck of flagged rows (sequential-fmaf form, matches np-passing R6/R7)
__global__ void exact_kernel(const float* __restrict__ x, const float* __restrict__ lut,
                             float* __restrict__ out, const float* __restrict__ ws) {
    __shared__ float xr[DIM];
    __shared__ float rv[256];
    __shared__ int   ri[256];
    const int cnt = ((const int*)ws)[WS_CNT_I];
    const int* list = (const int*)ws + WS_LIST_I;
    const int tid = threadIdx.x;
    for (int ii = blockIdx.x; ii < cnt; ii += gridDim.x) {
        const int row = list[ii];
        const int b = row >> 10, hw = row & 1023;
        __syncthreads();
        xr[tid] = x[(size_t)b * (DIM * HW) + (size_t)tid * HW + hw];
        __syncthreads();
        float bv = 3.4e38f; int bi = 0;
        #pragma unroll
        for (int k2 = 0; k2 < 2; ++k2) {
            int k = tid + k2 * 256;
            const float* cr = lut + (size_t)k * DIM;
            float dot = 0.f;
            for (int d = 0; d < DIM; ++d) dot = fmaf(xr[d], cr[d], dot);
            float dist = fmaf(-2.f, dot, ws[k]);
            if (dist < bv || (dist == bv && k < bi)) { bv = dist; bi = k; }
        }
        rv[tid] = bv; ri[tid] = bi;
        __syncthreads();
        for (int s = 128; s; s >>= 1) {
            if (tid < s) {
                float ov = rv[tid + s]; int oi = ri[tid + s];
                if (ov < rv[tid] || (ov == rv[tid] && oi < ri[tid])) {
                    rv[tid] = ov; ri[tid] = oi;
                }
            }
            __syncthreads();
        }
        const int q = ri[0];
        if (tid == 0) out[OUT_Q_OFF + row] = (float)q;
        out[(size_t)b * (DIM * HW) + (size_t)tid * HW + hw] = lut[(size_t)q * DIM + tid];
    }
}

__global__ void loss_kernel(float* __restrict__ out, const float* __restrict__ ws) {
    __shared__ float wsum[4];
    int tid = threadIdx.x;
    float s = 0.f;
    for (int i = tid; i < 1024; i += 256) s += ws[WS_DIST + i];
    #pragma unroll
    for (int off = 32; off; off >>= 1) s += __shfl_down(s, off, 64);
    if ((tid & 63) == 0) wsum[tid >> 6] = s;
    __syncthreads();
    if (tid == 0) {
        float total = wsum[0] + wsum[1] + wsum[2] + wsum[3];
        out[OUT_LOSS_OFF] = total * (1.25f / 16777216.f);
    }
}

extern "C" void kernel_launch(void* const* d_in, const int* in_sizes, int n_in,
                              void* d_out, int out_size, void* d_ws, size_t ws_size,
                              hipStream_t stream) {
    const float* x   = (const float*)d_in[0];
    const float* lut = (const float*)d_in[1];
    float* out = (float*)d_out;
    float* ws  = (float*)d_ws;

    (void)hipFuncSetAttribute((const void*)vq_kernel,
                              hipFuncAttributeMaxDynamicSharedMemorySize, VQ_LDS);

    c2_kernel<<<1, 256, 0, stream>>>(lut, ws);
    lutprep_kernel<<<64, 256, 0, stream>>>(lut, ws);
    vq_kernel<<<NBLK, NT, VQ_LDS, stream>>>(x, lut, out, ws);
    exact_kernel<<<2048, 256, 0, stream>>>(x, lut, out, ws);
    loss_kernel<<<1, 256, 0, stream>>>(out, ws);
}